// Round 3
// baseline (123.379 us; speedup 1.0000x reference)
//
#include <hip/hip_runtime.h>

typedef unsigned int  u32;
typedef unsigned short u16;

typedef float    f4  __attribute__((ext_vector_type(4)));
typedef short    bf8 __attribute__((ext_vector_type(8)));
typedef __fp16   h8  __attribute__((ext_vector_type(8)));
typedef __fp16   h2  __attribute__((ext_vector_type(2)));

#define NBLK  1024
#define ITERS 4      // must be even; 1024 * 4 * 64 = 262144 boards
#define ZSTR  104    // z1 row stride (u16); 52 dw/row; 16B-aligned rows (b128) + 2-way-max banks

// ---- workspace layout (bytes); total 59280 ----
#define WS_AF   0        // u16[4*4*3*512]  = 49152 B : W1 bf16, K+M-permuted, lane-ordered
#define WS_OW   49152    // u32[4*2*64*4]   =  8192 B : out_w fp16-pair A-frags, lane-ordered
#define WS_TAB  57344    // uint2[242]      =  1936 B : Th[0..120], Tv[121..241]

// fp32 -> bf16 bits, round-half-up (weights only; ties are measure-zero)
__device__ __forceinline__ u32 bfr(float f) {
    union { float f; u32 u; } v; v.f = f;
    return (v.u + 0x8000u) >> 16;
}
__device__ __forceinline__ u32 pk2(float lo, float hi) { return bfr(lo) | (bfr(hi) << 16); }
__device__ __forceinline__ u32 pkh(float lo, float hi) {   // fp16 pair (RTZ, 1 inst)
    union { h2 h; u32 u; } v; v.h = __builtin_amdgcn_cvt_pkrtz(lo, hi); return v.u;
}
// packed fp16 relu: one v_pk_max_f16 against 0 (inline asm; ROCm 7.2 __hmax2 header is broken)
__device__ __forceinline__ u32 pkmax0(u32 x) {
    u32 r; asm("v_pk_max_f16 %0, %1, %2" : "=v"(r) : "v"(x), "v"(0u)); return r;
}
__device__ __forceinline__ u32 nrev(u32 x) {
    return ((x >> 12) & 0xFu) | ((x >> 4) & 0xF0u) | ((x << 4) & 0xF00u) | ((x << 12) & 0xF000u);
}

// ======================= prep kernel: per-LAUNCH weight transform =======================
__launch_bounds__(256)
__global__ void smartcnn_prep(const float* __restrict__ c0w, const float* __restrict__ c0b,
                              const float* __restrict__ c1w,
                              const float* __restrict__ lw,  const float* __restrict__ ow,
                              u16* __restrict__ wsAf, u32* __restrict__ wsOw,
                              uint2* __restrict__ wsTab)
{
    const int i = blockIdx.x * 256 + threadIdx.x;
    if (i < 24576) {
        // af element: i = ((w*4+tt)*3+s)*512 + (qd*16+m)*8 + j
        const int j    = i & 7;
        const int lane = (i >> 3) & 63;
        const int rest = i >> 9;
        const int m  = lane & 15, qd = lane >> 4;
        const int s  = rest % 3;
        const int wtt = rest / 3;
        const int tt = wtt & 3, w = wtt >> 2;
        const int tbase = ((tt & 1) ? 4 : 0) + ((tt >> 1) ? 32 : 0);
        const int fid = 64*w + tbase + 8*(m >> 2) + (m & 3);        // M-permuted feature row
        const int kp = s*32 + qd*8 + j;                              // fragment K position
        const int kq = (kp < 48) ? kp : kp - 48;                     // invert K-permutation:
        const int ko = ((kp < 48) ? 0 : 48) + (kq & 3)*12 + (kq >> 2); // kp=(ko%12)*4+ko/12
        wsAf[i] = (u16)bfr(lw[fid*96 + ko]);
    } else if (i < 26624) {
        // out_w fp16-pair element: t = ((w*2+c)*64 + qd*16+m)*4 + k
        const int t = i - 24576;
        const int k    = t & 3;
        const int lane = (t >> 2) & 63;
        const int wc   = t >> 8;
        const int m = lane & 15, qd = lane >> 4;
        const int c = wc & 1, w = wc >> 1;
        u32 val = 0u;
        if (m < 4) {   // rows 0-3 = actions, rows 4-15 = 0
            const int n8 = 64*w + 32*c + qd*8;
            val = pkh(ow[m*256 + n8 + 2*k], ow[m*256 + n8 + 2*k + 1]);
        }
        wsOw[t] = val;
    } else if (i < 26866) {
        // conv pair tables: t<121 -> Th (conv0 pair + bias), else Tv (conv1 pair)
        const int t = i - 26624;
        const int e = (t < 121) ? t : t - 121;
        const int v1 = e / 11, v2 = e - v1*11;
        float a[4];
        #pragma unroll
        for (int c = 0; c < 4; ++c) {
            if (t < 121)
                a[c] = fmaxf(c0w[c*24 + 0] + c0w[c*24 + (1+v1)*2 + 0] + c0b[c]
                           + c0w[c*24 + 1] + c0w[c*24 + (1+v2)*2 + 1], 0.f);
            else
                a[c] = fmaxf(c1w[c*24 + 0] + c1w[c*24 + (1+v1)*2 + 0]
                           + c1w[c*24 + 1] + c1w[c*24 + (1+v2)*2 + 1], 0.f);
        }
        wsTab[t] = make_uint2(pk2(a[0], a[1]), pk2(a[2], a[3]));
    }
}

// ---- phase 1: build z1 rows + flip flags for this wave's 16 boards ----
__device__ __forceinline__ void phase1_fn(const int4 e4, u16* __restrict__ z1b, u32* __restrict__ flgb,
                                          const uint2* __restrict__ Th, const uint2* __restrict__ Tv,
                                          const int w, const int m, const int qd)
{
    u32 pkd = (u32)e4.x | ((u32)e4.y << 4) | ((u32)e4.z << 8) | ((u32)e4.w << 12);
    u32 R0 = (u32)__shfl((int)pkd, m);
    u32 R1 = (u32)__shfl((int)pkd, m + 16);
    u32 R2 = (u32)__shfl((int)pkd, m + 32);
    u32 R3 = (u32)__shfl((int)pkd, m + 48);
    u32 c0v = R0 & 15u, c1v = (R0 >> 12) & 15u, c2v = R3 & 15u, c3v = (R3 >> 12) & 15u;
    u32 best = c0v; int ix = 0;
    if (c1v > best) { best = c1v; ix = 1; }
    if (c2v > best) { best = c2v; ix = 2; }
    if (c3v > best) { best = c3v; ix = 3; }
    const bool fv = (ix >= 2), fh = ((ix & 1) != 0);
    u32 F[4];
    F[0] = fv ? R3 : R0;
    F[1] = fv ? R2 : R1;
    F[2] = fv ? R1 : R2;
    F[3] = fv ? R0 : R3;
    #pragma unroll
    for (int i = 0; i < 4; ++i) F[i] = fh ? nrev(F[i]) : F[i];

    if (qd == 0) flgb[w*16 + m] = (u32)fv | ((u32)fh << 1);

    const u32 Fq = F[qd];
    u32 nbq[4], nbc[4];
    #pragma unroll
    for (int j = 0; j < 4; ++j) nbq[j] = (Fq >> (4*j)) & 15u;
    #pragma unroll
    for (int i = 0; i < 4; ++i) nbc[i] = (F[i] >> (4*qd)) & 15u;

    uint2 H0 = Th[nbq[0]*11u + nbq[1]];
    uint2 H1 = Th[nbq[1]*11u + nbq[2]];
    uint2 H2 = Th[nbq[2]*11u + nbq[3]];
    uint2 V0 = Tv[nbc[0]*11u + nbc[1]];
    uint2 V1 = Tv[nbc[1]*11u + nbc[2]];
    uint2 V2 = Tv[nbc[2]*11u + nbc[3]];

    u16* zrow = &z1b[(w*16 + m) * ZSTR];
    *(uint2*)(zrow + (qd*3 + 0)*4) = H0;
    *(uint2*)(zrow + (qd*3 + 1)*4) = H1;
    *(uint2*)(zrow + (qd*3 + 2)*4) = H2;
    *(uint2*)(zrow + 48 + (0*4 + qd)*4) = V0;
    *(uint2*)(zrow + 48 + (1*4 + qd)*4) = V1;
    *(uint2*)(zrow + 48 + (2*4 + qd)*4) = V2;
}

// ---- GEMM1 (bf16 MFMA) -> fp16 pack + packed relu -> GEMM2 (f16 MFMA) -> Pbuf partials ----
__device__ __forceinline__ void gemm_fn(const u16* __restrict__ z1b, float4* __restrict__ Pb,
                                        const bf8 (&af)[4][3], const u32 (&owA)[2][4], const f4 (&lb4)[4],
                                        const int w, const int m, const int qd)
{
    // hoist ALL 12 b128 LDS reads: independent issues, one lgkm drain, MLP instead of 4 serial waits
    bf8 zb[4][3];
    #pragma unroll
    for (int G = 0; G < 4; ++G)
        #pragma unroll
        for (int s = 0; s < 3; ++s)
            zb[G][s] = *(const bf8*)(&z1b[(G*16 + m)*ZSTR + s*32 + qd*8]);

    __builtin_amdgcn_s_setprio(1);
    #pragma unroll
    for (int G = 0; G < 4; ++G) {
        f4 acc_t[4] = {lb4[0], lb4[1], lb4[2], lb4[3]};
        #pragma unroll
        for (int s = 0; s < 3; ++s)
            #pragma unroll
            for (int tt = 0; tt < 4; ++tt)
                acc_t[tt] = __builtin_amdgcn_mfma_f32_16x16x32_bf16(af[tt][s], zb[G][s], acc_t[tt], 0, 0, 0);

        // M-permutation: lane (qd,m)'s acc rows = features 32c+8qd+j of board m -> in-lane B-frag
        f4 acc2 = {0.f, 0.f, 0.f, 0.f};
        #pragma unroll
        for (int c = 0; c < 2; ++c) {
            union { u32 u[4]; h8 v; } bu, au;
            bu.u[0] = pkmax0(pkh(acc_t[2*c  ][0], acc_t[2*c  ][1]));
            bu.u[1] = pkmax0(pkh(acc_t[2*c  ][2], acc_t[2*c  ][3]));
            bu.u[2] = pkmax0(pkh(acc_t[2*c+1][0], acc_t[2*c+1][1]));
            bu.u[3] = pkmax0(pkh(acc_t[2*c+1][2], acc_t[2*c+1][3]));
            au.u[0] = owA[c][0]; au.u[1] = owA[c][1]; au.u[2] = owA[c][2]; au.u[3] = owA[c][3];
            acc2 = __builtin_amdgcn_mfma_f32_16x16x32_f16(au.v, bu.v, acc2, 0, 0, 0);
        }
        if (qd == 0)
            Pb[(G*4 + w)*16 + m] = make_float4(acc2[0], acc2[1], acc2[2], acc2[3]);
    }
    __builtin_amdgcn_s_setprio(0);
}

// ---- epilogue, split: load Pb partials early (LDS latency overlaps phase1), compute later ----
struct P4 { float4 a, b, c, d; };
__device__ __forceinline__ P4 epi_load(const float4* __restrict__ Pb, const int m, const int qd)
{
    P4 r;
    r.a = Pb[(qd*4 + 0)*16 + m];
    r.b = Pb[(qd*4 + 1)*16 + m];
    r.c = Pb[(qd*4 + 2)*16 + m];
    r.d = Pb[(qd*4 + 3)*16 + m];
    return r;
}
__device__ __forceinline__ void epi_compute(const P4 s, const u32 fl, const float4 obv,
                                            float* __restrict__ out, const int base, const int m, const int qd)
{
    float L0 = s.a.x + s.b.x + s.c.x + s.d.x + obv.x;
    float L1 = s.a.y + s.b.y + s.c.y + s.d.y + obv.y;
    float L2 = s.a.z + s.b.z + s.c.z + s.d.z + obv.z;
    float L3 = s.a.w + s.b.w + s.c.w + s.d.w + obv.w;
    float mx = fmaxf(fmaxf(L0, L1), fmaxf(L2, L3));
    float e0 = __expf(L0 - mx), e1 = __expf(L1 - mx), e2 = __expf(L2 - mx), e3 = __expf(L3 - mx);
    float inv = __builtin_amdgcn_rcpf(e0 + e1 + e2 + e3);   // ~1 ulp; prob err ~1e-7
    float p0 = e0 * inv, p1 = e1 * inv, p2 = e2 * inv, p3 = e3 * inv;
    float4 o;
    o.x = (fl & 1u) ? p1 : p0;
    o.y = (fl & 1u) ? p0 : p1;
    o.z = (fl & 2u) ? p3 : p2;
    o.w = (fl & 2u) ? p2 : p3;
    *(float4*)(out + (size_t)(base + qd*16 + m) * 4) = o;
}

__launch_bounds__(256, 4)
__global__ void smartcnn_fused(const int* __restrict__ exps,
                               const float* __restrict__ lb, const float* __restrict__ ob,
                               const u16* __restrict__ wsAf, const u32* __restrict__ wsOw,
                               const uint2* __restrict__ wsTab,
                               float* __restrict__ out)
{
    __shared__ uint2  ThA[121];          // [v1*11+v2] -> 4 channels bf16 (relu(conv0 pair + bias))
    __shared__ uint2  TvA[121];          // [v1*11+v2] -> 4 channels bf16 (relu(conv1 pair))
    __shared__ u16    z1A[64 * ZSTR];    // double-buffered z1 (STATIC names -> no dynamic indexing)
    __shared__ u16    z1B[64 * ZSTR];
    __shared__ float4 PbA[4*4*16];       // double-buffered logit partials [(G*4+w)*16+m]
    __shared__ float4 PbB[4*4*16];
    __shared__ u32    flgA[64];          // double-buffered flip flags
    __shared__ u32    flgB[64];

    const int tid  = threadIdx.x;
    const int w    = tid >> 6;
    const int lane = tid & 63;
    const int m    = lane & 15;
    const int qd   = lane >> 4;

    // ---- tables: one coalesced uint2 load per thread from prep output ----
    if (tid < 242) {
        uint2 v = wsTab[tid];
        if (tid < 121) ThA[tid] = v; else TvA[tid - 121] = v;
    }

    // ---- W1 A-fragments (48 VGPR): direct coalesced dwordx4 loads, no staging, no VALU ----
    bf8 af[4][3];
    #pragma unroll
    for (int tt = 0; tt < 4; ++tt)
        #pragma unroll
        for (int s = 0; s < 3; ++s)
            af[tt][s] = *(const bf8*)(wsAf + (((w*4 + tt)*3 + s) << 9) + (lane << 3));

    // ---- out_w A-fragments, fp16 (8 VGPR): one dwordx4 per c ----
    u32 owA[2][4];
    #pragma unroll
    for (int c = 0; c < 2; ++c) {
        uint4 t = *(const uint4*)(wsOw + ((((w*2 + c) << 6) + lane) << 2));
        owA[c][0] = t.x; owA[c][1] = t.y; owA[c][2] = t.z; owA[c][3] = t.w;
    }

    // ---- linear_b as f4, M-permuted: lb4[tt][r] = lb[64w + tbase(tt) + 8qd + r] ----
    f4 lb4[4];
    #pragma unroll
    for (int tt = 0; tt < 4; ++tt) {
        const int tbase = ((tt & 1) ? 4 : 0) + ((tt >> 1) ? 32 : 0);
        lb4[tt] = *(const f4*)(lb + 64*w + tbase + 8*qd);
    }
    const float4 obv = *(const float4*)ob;

    const int b0 = blockIdx.x * (ITERS * 64);
    __syncthreads();  // tables published

    // ---- pre-loop: fill A buffers for it=0 ----
    int4 e4 = *(const int4*)(exps + (size_t)(b0 + w*16 + m)*16 + qd*4);
    phase1_fn(e4, z1A, flgA, &ThA[0], &TvA[0], w, m, qd);
    e4 = *(const int4*)(exps + (size_t)(b0 + 64 + w*16 + m)*16 + qd*4);
    __syncthreads();  // z1A/flgA (it=0) published

    // ---- pipelined pair loop: 1 barrier per iteration, work on both sides ----
    #pragma unroll
    for (int itp = 0; itp < ITERS/2; ++itp) {
        const int it = itp * 2;

        const u32 flA = flgA[qd*16 + m];              // it data (published)
        phase1_fn(e4, z1B, flgB, &ThA[0], &TvA[0], w, m, qd);   // it+1 -> B
        if (it + 2 < ITERS)
            e4 = *(const int4*)(exps + (size_t)(b0 + (it+2)*64 + w*16 + m)*16 + qd*4);
        gemm_fn(z1A, PbA, af, owA, lb4, w, m, qd);    // it

        __syncthreads();  // b1: PbA + z1B/flgB published; all z1A readers retired

        const u32 flB = flgB[qd*16 + m];              // it+1 data (published at b1)
        P4 sA = epi_load(PbA, m, qd);                 // issue Pb reads NOW; latency hides under phase1
        if (it + 2 < ITERS) {
            phase1_fn(e4, z1A, flgA, &ThA[0], &TvA[0], w, m, qd);   // it+2 -> A (gathers issue early)
            if (it + 3 < ITERS)
                e4 = *(const int4*)(exps + (size_t)(b0 + (it+3)*64 + w*16 + m)*16 + qd*4);
        }
        epi_compute(sA, flA, obv, out, b0 + it*64, m, qd);   // epi VALU hides phase1 gather latency
        gemm_fn(z1B, PbB, af, owA, lb4, w, m, qd);    // it+1

        __syncthreads();  // b2: PbB + z1A/flgA(it+2) published; all z1B readers retired

        P4 sB = epi_load(PbB, m, qd);
        epi_compute(sB, flB, obv, out, b0 + (it+1)*64, m, qd);
        // next pair's phase1(it+3)->B only touches z1B/flgB, whose readers retired at b2
    }
}

extern "C" void kernel_launch(void* const* d_in, const int* in_sizes, int n_in,
                              void* d_out, int out_size, void* d_ws, size_t ws_size,
                              hipStream_t stream) {
    const int*   exps = (const int*)  d_in[0];
    const float* c0w  = (const float*)d_in[1];
    const float* c0b  = (const float*)d_in[2];
    const float* c1w  = (const float*)d_in[3];
    const float* lw   = (const float*)d_in[4];
    const float* lbv  = (const float*)d_in[5];
    const float* oww  = (const float*)d_in[6];
    const float* obv  = (const float*)d_in[7];
    u16*   wsAf  = (u16*)  ((char*)d_ws + WS_AF);
    u32*   wsOw  = (u32*)  ((char*)d_ws + WS_OW);
    uint2* wsTab = (uint2*)((char*)d_ws + WS_TAB);
    // prep: 26866 elements, 105 blocks x 256 threads, ~2-3 us
    smartcnn_prep<<<105, 256, 0, stream>>>(c0w, c0b, c1w, lw, oww, wsAf, wsOw, wsTab);
    smartcnn_fused<<<NBLK, 256, 0, stream>>>(exps, lbv, obv, wsAf, wsOw, wsTab, (float*)d_out);
}

// Round 4
// 91.496 us; speedup vs baseline: 1.3485x; 1.3485x over previous
//
#include <hip/hip_runtime.h>

typedef unsigned int  u32;
typedef unsigned short u16;

typedef float    f4  __attribute__((ext_vector_type(4)));
typedef short    bf8 __attribute__((ext_vector_type(8)));
typedef __fp16   h8  __attribute__((ext_vector_type(8)));
typedef __fp16   h2  __attribute__((ext_vector_type(2)));

#define NBLK  1024
#define ITERS 4      // must be even; 1024 * 4 * 64 = 262144 boards
#define ZSTR  104    // z1 row stride (u16); 52 dw/row; 16B-aligned rows (b128) + 2-way-max banks

// ---- workspace layout (bytes); total 59280 ----
#define WS_AF   0        // u16[4*4*3*512]  = 49152 B : W1 bf16, K+M-permuted, lane-ordered
#define WS_OW   49152    // u32[4*2*64*4]   =  8192 B : out_w fp16-pair A-frags, lane-ordered
#define WS_TAB  57344    // uint2[242]      =  1936 B : Th[0..120], Tv[121..241]

// fp32 -> bf16 bits, round-half-up (weights only; ties are measure-zero)
__device__ __forceinline__ u32 bfr(float f) {
    union { float f; u32 u; } v; v.f = f;
    return (v.u + 0x8000u) >> 16;
}
__device__ __forceinline__ u32 pk2(float lo, float hi) { return bfr(lo) | (bfr(hi) << 16); }
__device__ __forceinline__ u32 pkh(float lo, float hi) {   // fp16 pair (RTZ, 1 inst)
    union { h2 h; u32 u; } v; v.h = __builtin_amdgcn_cvt_pkrtz(lo, hi); return v.u;
}
// packed fp16 relu: one v_pk_max_f16 against 0 (inline asm; ROCm 7.2 __hmax2 header is broken)
__device__ __forceinline__ u32 pkmax0(u32 x) {
    u32 r; asm("v_pk_max_f16 %0, %1, %2" : "=v"(r) : "v"(x), "v"(0u)); return r;
}
__device__ __forceinline__ u32 nrev(u32 x) {
    return ((x >> 12) & 0xFu) | ((x >> 4) & 0xF0u) | ((x << 4) & 0xF00u) | ((x << 12) & 0xF000u);
}

// ======================= prep kernel: per-LAUNCH weight transform =======================
__launch_bounds__(256)
__global__ void smartcnn_prep(const float* __restrict__ c0w, const float* __restrict__ c0b,
                              const float* __restrict__ c1w,
                              const float* __restrict__ lw,  const float* __restrict__ ow,
                              u16* __restrict__ wsAf, u32* __restrict__ wsOw,
                              uint2* __restrict__ wsTab)
{
    const int i = blockIdx.x * 256 + threadIdx.x;
    if (i < 24576) {
        // af element: i = ((w*4+tt)*3+s)*512 + (qd*16+m)*8 + j
        const int j    = i & 7;
        const int lane = (i >> 3) & 63;
        const int rest = i >> 9;
        const int m  = lane & 15, qd = lane >> 4;
        const int s  = rest % 3;
        const int wtt = rest / 3;
        const int tt = wtt & 3, w = wtt >> 2;
        const int tbase = ((tt & 1) ? 4 : 0) + ((tt >> 1) ? 32 : 0);
        const int fid = 64*w + tbase + 8*(m >> 2) + (m & 3);        // M-permuted feature row
        const int kp = s*32 + qd*8 + j;                              // fragment K position
        const int kq = (kp < 48) ? kp : kp - 48;                     // invert K-permutation:
        const int ko = ((kp < 48) ? 0 : 48) + (kq & 3)*12 + (kq >> 2); // kp=(ko%12)*4+ko/12
        wsAf[i] = (u16)bfr(lw[fid*96 + ko]);
    } else if (i < 26624) {
        // out_w fp16-pair element: t = ((w*2+c)*64 + qd*16+m)*4 + k
        const int t = i - 24576;
        const int k    = t & 3;
        const int lane = (t >> 2) & 63;
        const int wc   = t >> 8;
        const int m = lane & 15, qd = lane >> 4;
        const int c = wc & 1, w = wc >> 1;
        u32 val = 0u;
        if (m < 4) {   // rows 0-3 = actions, rows 4-15 = 0
            const int n8 = 64*w + 32*c + qd*8;
            val = pkh(ow[m*256 + n8 + 2*k], ow[m*256 + n8 + 2*k + 1]);
        }
        wsOw[t] = val;
    } else if (i < 26866) {
        // conv pair tables: t<121 -> Th (conv0 pair + bias), else Tv (conv1 pair)
        const int t = i - 26624;
        const int e = (t < 121) ? t : t - 121;
        const int v1 = e / 11, v2 = e - v1*11;
        float a[4];
        #pragma unroll
        for (int c = 0; c < 4; ++c) {
            if (t < 121)
                a[c] = fmaxf(c0w[c*24 + 0] + c0w[c*24 + (1+v1)*2 + 0] + c0b[c]
                           + c0w[c*24 + 1] + c0w[c*24 + (1+v2)*2 + 1], 0.f);
            else
                a[c] = fmaxf(c1w[c*24 + 0] + c1w[c*24 + (1+v1)*2 + 0]
                           + c1w[c*24 + 1] + c1w[c*24 + (1+v2)*2 + 1], 0.f);
        }
        wsTab[t] = make_uint2(pk2(a[0], a[1]), pk2(a[2], a[3]));
    }
}

// ---- phase 1: build z1 rows + flip flags for this wave's 16 boards ----
__device__ __forceinline__ void phase1_fn(const int4 e4, u16* __restrict__ z1b, u32* __restrict__ flgb,
                                          const uint2* __restrict__ Th, const uint2* __restrict__ Tv,
                                          const int w, const int m, const int qd)
{
    u32 pkd = (u32)e4.x | ((u32)e4.y << 4) | ((u32)e4.z << 8) | ((u32)e4.w << 12);
    u32 R0 = (u32)__shfl((int)pkd, m);
    u32 R1 = (u32)__shfl((int)pkd, m + 16);
    u32 R2 = (u32)__shfl((int)pkd, m + 32);
    u32 R3 = (u32)__shfl((int)pkd, m + 48);
    u32 c0v = R0 & 15u, c1v = (R0 >> 12) & 15u, c2v = R3 & 15u, c3v = (R3 >> 12) & 15u;
    u32 best = c0v; int ix = 0;
    if (c1v > best) { best = c1v; ix = 1; }
    if (c2v > best) { best = c2v; ix = 2; }
    if (c3v > best) { best = c3v; ix = 3; }
    const bool fv = (ix >= 2), fh = ((ix & 1) != 0);
    u32 F[4];
    F[0] = fv ? R3 : R0;
    F[1] = fv ? R2 : R1;
    F[2] = fv ? R1 : R2;
    F[3] = fv ? R0 : R3;
    #pragma unroll
    for (int i = 0; i < 4; ++i) F[i] = fh ? nrev(F[i]) : F[i];

    if (qd == 0) flgb[w*16 + m] = (u32)fv | ((u32)fh << 1);

    const u32 Fq = F[qd];
    u32 nbq[4], nbc[4];
    #pragma unroll
    for (int j = 0; j < 4; ++j) nbq[j] = (Fq >> (4*j)) & 15u;
    #pragma unroll
    for (int i = 0; i < 4; ++i) nbc[i] = (F[i] >> (4*qd)) & 15u;

    uint2 H0 = Th[nbq[0]*11u + nbq[1]];
    uint2 H1 = Th[nbq[1]*11u + nbq[2]];
    uint2 H2 = Th[nbq[2]*11u + nbq[3]];
    uint2 V0 = Tv[nbc[0]*11u + nbc[1]];
    uint2 V1 = Tv[nbc[1]*11u + nbc[2]];
    uint2 V2 = Tv[nbc[2]*11u + nbc[3]];

    u16* zrow = &z1b[(w*16 + m) * ZSTR];
    *(uint2*)(zrow + (qd*3 + 0)*4) = H0;
    *(uint2*)(zrow + (qd*3 + 1)*4) = H1;
    *(uint2*)(zrow + (qd*3 + 2)*4) = H2;
    *(uint2*)(zrow + 48 + (0*4 + qd)*4) = V0;
    *(uint2*)(zrow + 48 + (1*4 + qd)*4) = V1;
    *(uint2*)(zrow + 48 + (2*4 + qd)*4) = V2;
}

// ---- GEMM1 (bf16 MFMA) -> fp16 pack + packed relu -> GEMM2 (f16 MFMA) -> Pbuf partials ----
// NOTE R3 post-mortem: do NOT hoist all 12 zb loads — +48 VGPR pushed past the 128-reg cap
// (launch_bounds 256,4) and spilled to scratch (WRITE_SIZE 4->40MB, main 42->56us). Per-G loads.
__device__ __forceinline__ void gemm_fn(const u16* __restrict__ z1b, float4* __restrict__ Pb,
                                        const bf8 (&af)[4][3], const u32 (&owA)[2][4], const f4 (&lb4)[4],
                                        const int w, const int m, const int qd)
{
    #pragma unroll
    for (int G = 0; G < 4; ++G) {
        bf8 zb[3];
        #pragma unroll
        for (int s = 0; s < 3; ++s)
            zb[s] = *(const bf8*)(&z1b[(G*16 + m)*ZSTR + s*32 + qd*8]);

        __builtin_amdgcn_s_setprio(1);
        f4 acc_t[4] = {lb4[0], lb4[1], lb4[2], lb4[3]};
        #pragma unroll
        for (int s = 0; s < 3; ++s)
            #pragma unroll
            for (int tt = 0; tt < 4; ++tt)
                acc_t[tt] = __builtin_amdgcn_mfma_f32_16x16x32_bf16(af[tt][s], zb[s], acc_t[tt], 0, 0, 0);

        // M-permutation: lane (qd,m)'s acc rows = features 32c+8qd+j of board m -> in-lane B-frag
        f4 acc2 = {0.f, 0.f, 0.f, 0.f};
        #pragma unroll
        for (int c = 0; c < 2; ++c) {
            union { u32 u[4]; h8 v; } bu, au;
            bu.u[0] = pkmax0(pkh(acc_t[2*c  ][0], acc_t[2*c  ][1]));
            bu.u[1] = pkmax0(pkh(acc_t[2*c  ][2], acc_t[2*c  ][3]));
            bu.u[2] = pkmax0(pkh(acc_t[2*c+1][0], acc_t[2*c+1][1]));
            bu.u[3] = pkmax0(pkh(acc_t[2*c+1][2], acc_t[2*c+1][3]));
            au.u[0] = owA[c][0]; au.u[1] = owA[c][1]; au.u[2] = owA[c][2]; au.u[3] = owA[c][3];
            acc2 = __builtin_amdgcn_mfma_f32_16x16x32_f16(au.v, bu.v, acc2, 0, 0, 0);
        }
        __builtin_amdgcn_s_setprio(0);
        if (qd == 0)
            Pb[(G*4 + w)*16 + m] = make_float4(acc2[0], acc2[1], acc2[2], acc2[3]);
    }
}

// ---- epilogue, split: load Pb partials early (LDS latency overlaps phase1), compute later ----
struct P4 { float4 a, b, c, d; };
__device__ __forceinline__ P4 epi_load(const float4* __restrict__ Pb, const int m, const int qd)
{
    P4 r;
    r.a = Pb[(qd*4 + 0)*16 + m];
    r.b = Pb[(qd*4 + 1)*16 + m];
    r.c = Pb[(qd*4 + 2)*16 + m];
    r.d = Pb[(qd*4 + 3)*16 + m];
    return r;
}
__device__ __forceinline__ void epi_compute(const P4 s, const u32 fl, const float4 obv,
                                            float* __restrict__ out, const int base, const int m, const int qd)
{
    float L0 = s.a.x + s.b.x + s.c.x + s.d.x + obv.x;
    float L1 = s.a.y + s.b.y + s.c.y + s.d.y + obv.y;
    float L2 = s.a.z + s.b.z + s.c.z + s.d.z + obv.z;
    float L3 = s.a.w + s.b.w + s.c.w + s.d.w + obv.w;
    float mx = fmaxf(fmaxf(L0, L1), fmaxf(L2, L3));
    float e0 = __expf(L0 - mx), e1 = __expf(L1 - mx), e2 = __expf(L2 - mx), e3 = __expf(L3 - mx);
    float inv = __builtin_amdgcn_rcpf(e0 + e1 + e2 + e3);   // ~1 ulp; prob err ~1e-7
    float p0 = e0 * inv, p1 = e1 * inv, p2 = e2 * inv, p3 = e3 * inv;
    float4 o;
    o.x = (fl & 1u) ? p1 : p0;
    o.y = (fl & 1u) ? p0 : p1;
    o.z = (fl & 2u) ? p3 : p2;
    o.w = (fl & 2u) ? p2 : p3;
    *(float4*)(out + (size_t)(base + qd*16 + m) * 4) = o;
}

__launch_bounds__(256, 4)
__global__ void smartcnn_fused(const int* __restrict__ exps,
                               const float* __restrict__ lb, const float* __restrict__ ob,
                               const u16* __restrict__ wsAf, const u32* __restrict__ wsOw,
                               const uint2* __restrict__ wsTab,
                               float* __restrict__ out)
{
    __shared__ uint2  ThA[121];          // [v1*11+v2] -> 4 channels bf16 (relu(conv0 pair + bias))
    __shared__ uint2  TvA[121];          // [v1*11+v2] -> 4 channels bf16 (relu(conv1 pair))
    __shared__ u16    z1A[64 * ZSTR];    // double-buffered z1 (STATIC names -> no dynamic indexing)
    __shared__ u16    z1B[64 * ZSTR];
    __shared__ float4 PbA[4*4*16];       // double-buffered logit partials [(G*4+w)*16+m]
    __shared__ float4 PbB[4*4*16];
    __shared__ u32    flgA[64];          // double-buffered flip flags
    __shared__ u32    flgB[64];

    const int tid  = threadIdx.x;
    const int w    = tid >> 6;
    const int lane = tid & 63;
    const int m    = lane & 15;
    const int qd   = lane >> 4;

    // ---- tables: one coalesced uint2 load per thread from prep output ----
    if (tid < 242) {
        uint2 v = wsTab[tid];
        if (tid < 121) ThA[tid] = v; else TvA[tid - 121] = v;
    }

    // ---- W1 A-fragments (48 VGPR): direct coalesced dwordx4 loads, no staging, no VALU ----
    bf8 af[4][3];
    #pragma unroll
    for (int tt = 0; tt < 4; ++tt)
        #pragma unroll
        for (int s = 0; s < 3; ++s)
            af[tt][s] = *(const bf8*)(wsAf + (((w*4 + tt)*3 + s) << 9) + (lane << 3));

    // ---- out_w A-fragments, fp16 (8 VGPR): one dwordx4 per c ----
    u32 owA[2][4];
    #pragma unroll
    for (int c = 0; c < 2; ++c) {
        uint4 t = *(const uint4*)(wsOw + ((((w*2 + c) << 6) + lane) << 2));
        owA[c][0] = t.x; owA[c][1] = t.y; owA[c][2] = t.z; owA[c][3] = t.w;
    }

    // ---- linear_b as f4, M-permuted: lb4[tt][r] = lb[64w + tbase(tt) + 8qd + r] ----
    f4 lb4[4];
    #pragma unroll
    for (int tt = 0; tt < 4; ++tt) {
        const int tbase = ((tt & 1) ? 4 : 0) + ((tt >> 1) ? 32 : 0);
        lb4[tt] = *(const f4*)(lb + 64*w + tbase + 8*qd);
    }
    const float4 obv = *(const float4*)ob;

    const int b0 = blockIdx.x * (ITERS * 64);
    __syncthreads();  // tables published

    // ---- pre-loop: fill A buffers for it=0 ----
    int4 e4 = *(const int4*)(exps + (size_t)(b0 + w*16 + m)*16 + qd*4);
    phase1_fn(e4, z1A, flgA, &ThA[0], &TvA[0], w, m, qd);
    e4 = *(const int4*)(exps + (size_t)(b0 + 64 + w*16 + m)*16 + qd*4);
    __syncthreads();  // z1A/flgA (it=0) published

    // ---- pipelined pair loop: 1 barrier per iteration, work on both sides ----
    #pragma unroll
    for (int itp = 0; itp < ITERS/2; ++itp) {
        const int it = itp * 2;

        const u32 flA = flgA[qd*16 + m];              // it data (published)
        phase1_fn(e4, z1B, flgB, &ThA[0], &TvA[0], w, m, qd);   // it+1 -> B
        if (it + 2 < ITERS)
            e4 = *(const int4*)(exps + (size_t)(b0 + (it+2)*64 + w*16 + m)*16 + qd*4);
        gemm_fn(z1A, PbA, af, owA, lb4, w, m, qd);    // it

        __syncthreads();  // b1: PbA + z1B/flgB published; all z1A readers retired

        const u32 flB = flgB[qd*16 + m];              // it+1 data (published at b1)
        P4 sA = epi_load(PbA, m, qd);                 // issue Pb reads NOW; latency hides under phase1
        if (it + 2 < ITERS) {
            phase1_fn(e4, z1A, flgA, &ThA[0], &TvA[0], w, m, qd);   // it+2 -> A (gathers issue early)
            if (it + 3 < ITERS)
                e4 = *(const int4*)(exps + (size_t)(b0 + (it+3)*64 + w*16 + m)*16 + qd*4);
        }
        epi_compute(sA, flA, obv, out, b0 + it*64, m, qd);   // epi VALU hides phase1 gather latency
        gemm_fn(z1B, PbB, af, owA, lb4, w, m, qd);    // it+1

        __syncthreads();  // b2: PbB + z1A/flgA(it+2) published; all z1B readers retired

        P4 sB = epi_load(PbB, m, qd);
        epi_compute(sB, flB, obv, out, b0 + (it+1)*64, m, qd);
        // next pair's phase1(it+3)->B only touches z1B/flgB, whose readers retired at b2
    }
}

extern "C" void kernel_launch(void* const* d_in, const int* in_sizes, int n_in,
                              void* d_out, int out_size, void* d_ws, size_t ws_size,
                              hipStream_t stream) {
    const int*   exps = (const int*)  d_in[0];
    const float* c0w  = (const float*)d_in[1];
    const float* c0b  = (const float*)d_in[2];
    const float* c1w  = (const float*)d_in[3];
    const float* lw   = (const float*)d_in[4];
    const float* lbv  = (const float*)d_in[5];
    const float* oww  = (const float*)d_in[6];
    const float* obv  = (const float*)d_in[7];
    u16*   wsAf  = (u16*)  ((char*)d_ws + WS_AF);
    u32*   wsOw  = (u32*)  ((char*)d_ws + WS_OW);
    uint2* wsTab = (uint2*)((char*)d_ws + WS_TAB);
    // prep: 26866 elements, 105 blocks x 256 threads, ~2-3 us
    smartcnn_prep<<<105, 256, 0, stream>>>(c0w, c0b, c1w, lw, oww, wsAf, wsOw, wsTab);
    smartcnn_fused<<<NBLK, 256, 0, stream>>>(exps, lbv, obv, wsAf, wsOw, wsTab, (float*)d_out);
}